// Round 25
// baseline (7049.739 us; speedup 1.0000x reference)
//
#include <hip/hip_runtime.h>

// r25: dual-chain pipeline (r20, best 4.66ms) at DOUBLE wave-specialization:
// 32 weights/lane. r24's assembler error proved gfx950 VALU cannot read
// AGPRs -> at 64 weights/lane the v_accvgpr_read per MAC (45% of busy) is
// unavoidable once RA banks weights in AGPRs (it always did, 7 rounds).
// At 32 weights/lane peak live ~60 regs fits the allocator's own preferred
// ~64-reg budget -> no AGPR banking, MAC = plain 2cy v_fmac.
// 512 blocks x 2 rows (chains A,B) x 1024 thr (16 waves):
//   G1-waves w<8:  own 32 hidden units x K-half; lane: u=32w+(l&31),
//                  kh=l>>5, holds W1[32kh+i][u] i=0..31. h-halves combined
//                  by __shfl_xor(32); k-assembly/RK4/x-publish as r20.
//   G2-waves w>=8: own K-slice [32g2,32g2+32) of W2; lane owns out-dim l.
//                  partials exchanged at stride-9 (2-way banks = free).
// Schedule/barriers verbatim r20: 1 lgkm-only barrier per slot, 8 slots
// per RK4 step serving both chains.

#define NB 1024
#define ND 64
#define NH 256
#define NBLK 512     // 2 rows per block
#define NTHR 1024    // 16 waves: 8x G1 + 8x G2

// LDS float offsets (2688 floats = 10.5 KB)
#define XBOF(C,W) (((C)<<9) + ((W)<<6))   // xb[2][8][64] per-chain per-G1-wave x
#define ABOF(C)   (1024 + ((C)<<8))       // ab[2][256] activations
#define PTOF(C)   (1536 + (C)*576)        // part[2][64*9] stride-9 partials
#define LDS_FL 2688

#define R32(M) M(0) M(1) M(2) M(3) M(4) M(5) M(6) M(7) M(8) M(9) \
  M(10) M(11) M(12) M(13) M(14) M(15) M(16) M(17) M(18) M(19) \
  M(20) M(21) M(22) M(23) M(24) M(25) M(26) M(27) M(28) M(29) M(30) M(31)

#define Q8(M) M(0,0,1,2,3) M(1,4,5,6,7) M(2,8,9,10,11) M(3,12,13,14,15) \
  M(4,16,17,18,19) M(5,20,21,22,23) M(6,24,25,26,27) M(7,28,29,30,31)

__device__ __forceinline__ float fast_tanh(float x) {
    float e = __expf(2.0f * x);
    float r = __builtin_amdgcn_rcpf(e + 1.0f);
    return 1.0f - 2.0f * r;
}

// lgkmcnt-only barrier: no vmcnt drain (out stores keep flowing).
#define BSYNC() do {                                             \
    asm volatile("s_waitcnt lgkmcnt(0)" ::: "memory");           \
    __builtin_amdgcn_s_barrier();                                \
    asm volatile("" ::: "memory");                               \
} while (0)

__global__ __launch_bounds__(NTHR)
void node_rk4_kernel(const float* __restrict__ y0,
                     const float* __restrict__ t,
                     const float* W1,
                     const float* b1,
                     const float* W2,
                     const float* b2,
                     float* __restrict__ out,
                     int nsteps)
{
    __shared__ float lds[LDS_FL];
    const int tid = threadIdx.x;
    const int w   = tid >> 6;        // wave 0..15
    const int l   = tid & 63;        // lane

    if (w < 8) {
        // ===== G1: k-assembly + RK4 + GEMM1(K-half) + tanh =====
        const int u    = (w << 5) + (l & 31);   // owned hidden unit
        const int kh32 = (l >> 5) << 5;         // K-half base (0 or 32)
        const float b1u = b1[u];
        const float b2l = b2[l];
        #define DW1(i) float w1_##i;
        R32(DW1)
        #define LW1(i) w1_##i = W1[(kh32 + (i)) * NH + u];
        R32(LW1)

        float* xbwA = lds + XBOF(0, w);
        float* xbwB = lds + XBOF(1, w);
        float* abA  = lds + ABOF(0);
        float* abB  = lds + ABOF(1);
        const float* prA = lds + PTOF(0);
        const float* prB = lds + PTOF(1);

        const int row0 = blockIdx.x * 2;
        float yA = y0[(row0 + 0) * ND + l];
        float yB = y0[(row0 + 1) * ND + l];
        float kaA = 0.0f, kaB = 0.0f;
        if (w == 0) {
            out[(size_t)(row0 + 0) * ND + l] = yA;   // step-0 output
            out[(size_t)(row0 + 1) * ND + l] = yB;
        }
        float dt = 0.0f, dt2 = 0.0f, dt6 = 0.0f;
        size_t obase = 0;

#define G1Q(q,i0,i1,i2,i3) { float4 xv_ = xq_[q]; \
    h0_ = fmaf(w1_##i0, xv_.x, h0_); h1_ = fmaf(w1_##i1, xv_.y, h1_); \
    h0_ = fmaf(w1_##i2, xv_.z, h0_); h1_ = fmaf(w1_##i3, xv_.w, h1_); }

// One G1 slot for chain C: assemble stage ST's k from 8 stride-9 partials
// (ST=0: init, x=y), RK4-advance x, GEMM1 on own K-half, combine halves
// via shfl_xor(32), tanh, publish a[u].
#define G1SLOT(C, CI, ST) do {                                       \
    float x_;                                                        \
    if ((ST) == 0) { x_ = y##C; }                                    \
    else {                                                           \
      const float* pr_ = pr##C + l * 9;                              \
      float kc_ = (((pr_[0] + pr_[1]) + (pr_[2] + pr_[3]))           \
                +  ((pr_[4] + pr_[5]) + (pr_[6] + pr_[7]))) + b2l;   \
      if ((ST)==1)      { ka##C  = kc_;       x_ = fmaf(dt2, kc_, y##C); } \
      else if ((ST)==2) { ka##C += 2.0f*kc_;  x_ = fmaf(dt2, kc_, y##C); } \
      else if ((ST)==3) { ka##C += 2.0f*kc_;  x_ = fmaf(dt,  kc_, y##C); } \
      else { y##C = fmaf(dt6, ka##C + kc_, y##C); x_ = y##C;         \
             if (w == 0) out[obase + (CI) * ND + l] = y##C; }        \
    }                                                                \
    xbw##C[l] = x_;                                                  \
    asm volatile("s_waitcnt lgkmcnt(0)" ::: "memory");               \
    const float4* xq_ = (const float4*)(xbw##C + kh32);              \
    float h0_ = 0.0f, h1_ = 0.0f;                                    \
    Q8(G1Q)                                                          \
    float hp_ = h0_ + h1_;                                           \
    float ho_ = __shfl_xor(hp_, 32, 64);                             \
    ab##C[u] = fast_tanh((hp_ + ho_) + b1u);                         \
} while (0)

        G1SLOT(A, 0, 0); BSYNC();     // slot 0
        G1SLOT(B, 1, 0); BSYNC();     // slot 1
        for (int s = 0; s < nsteps; ++s) {
            dt = t[s + 1] - t[s]; dt2 = 0.5f * dt; dt6 = dt * (1.0f / 6.0f);
            obase = (size_t)(s + 1) * (NB * ND) + (size_t)row0 * ND;
            G1SLOT(A, 0, 1); BSYNC();  G1SLOT(B, 1, 1); BSYNC();
            G1SLOT(A, 0, 2); BSYNC();  G1SLOT(B, 1, 2); BSYNC();
            G1SLOT(A, 0, 3); BSYNC();  G1SLOT(B, 1, 3); BSYNC();
            G1SLOT(A, 0, 4); BSYNC();  G1SLOT(B, 1, 4); BSYNC();
        }
    } else {
        // ===== G2: GEMM2 K-slice partials (chain-alternating) =====
        const int g2 = w - 8;                  // owned K-slice [32g2,32g2+32)
        #define DW2(i) float w2_##i;
        R32(DW2)
        #define LW2(i) w2_##i = W2[((g2 << 5) + (i)) * ND + l];
        R32(LW2)

        const float4* aqA = (const float4*)(lds + ABOF(0) + (g2 << 5));
        const float4* aqB = (const float4*)(lds + ABOF(1) + (g2 << 5));
        float* pwA = lds + PTOF(0);
        float* pwB = lds + PTOF(1);

#define G2Q(q,i0,i1,i2,i3) { float4 av_ = aq_[q]; \
    p0_ = fmaf(w2_##i0, av_.x, p0_); p1_ = fmaf(w2_##i1, av_.y, p1_); \
    p0_ = fmaf(w2_##i2, av_.z, p0_); p1_ = fmaf(w2_##i3, av_.w, p1_); }

#define G2SLOT(C) do {                                               \
    const float4* aq_ = aq##C;                                       \
    float p0_ = 0.0f, p1_ = 0.0f;                                    \
    Q8(G2Q)                                                          \
    pw##C[l * 9 + g2] = p0_ + p1_;   /* stride-9: 2-way banks, free */ \
} while (0)

        BSYNC();                      // slot 0 (idle)
        G2SLOT(A); BSYNC();           // slot 1: A's k1 partials
        for (int s = 0; s < nsteps; ++s) {
            G2SLOT(B); BSYNC();  G2SLOT(A); BSYNC();
            G2SLOT(B); BSYNC();  G2SLOT(A); BSYNC();
            G2SLOT(B); BSYNC();  G2SLOT(A); BSYNC();
            G2SLOT(B); BSYNC();  G2SLOT(A); BSYNC();
        }
    }
}

extern "C" void kernel_launch(void* const* d_in, const int* in_sizes, int n_in,
                              void* d_out, int out_size, void* d_ws, size_t ws_size,
                              hipStream_t stream) {
    const float* y0 = (const float*)d_in[0];
    const float* t  = (const float*)d_in[1];
    const float* W1 = (const float*)d_in[2];
    const float* b1 = (const float*)d_in[3];
    const float* W2 = (const float*)d_in[4];
    const float* b2 = (const float*)d_in[5];
    float* out = (float*)d_out;
    int nsteps = in_sizes[1] - 1;
    hipLaunchKernelGGL(node_rk4_kernel, dim3(NBLK), dim3(NTHR), 0, stream,
                       y0, t, W1, b1, W2, b2, out, nsteps);
}